// Round 13
// baseline (265.214 us; speedup 1.0000x reference)
//
#include <hip/hip_runtime.h>
#include <hip/hip_bf16.h>
#include <math.h>

#define HW_ (192*192)
#define Wd 192
#define HIDc 127
#define NBLK1 (HW_/64)   // 576 ln1qkv blocks
#define NTILE2 (HW_/32)  // 1152 attnfuse half-tiles

// fp32 weight-copy offsets inside ws "wts" region
// (O_WIN/O_WDW/O_WOUT shifted +1 so every weight row base is 8B-aligned.)
#define O_LN1W 0
#define O_QKVW 96
#define O_QKVB 7008
#define O_RPB  7152
#define O_PROJW 7490
#define O_PROJB 9794
#define O_ECA  9842
#define O_LN2W 9849
#define O_WIN  9946
#define O_WDW  22138
#define O_WOUT 24424
#define WTS_LEN 30520

typedef unsigned short ushort_t;
typedef _Float16 half2_t __attribute__((ext_vector_type(2)));
typedef float f32x2 __attribute__((ext_vector_type(2)));

__device__ __forceinline__ float b2f(__hip_bfloat16 v){ return __bfloat162float(v); }
__device__ __forceinline__ float u2f(ushort_t h){ return __uint_as_float(((unsigned)h)<<16); }
__device__ __forceinline__ ushort_t f2u(float f){
    __hip_bfloat16 h = __float2bfloat16(f);
    union { __hip_bfloat16 b; ushort_t u; } c; c.b = h; return c.u;
}
// unpack packed 2xbf16 (low index in low 16 bits)
__device__ __forceinline__ void up2(unsigned u, float& a, float& b){
    a = __uint_as_float(u << 16);
    b = __uint_as_float(u & 0xffff0000u);
}
// pack two f32 -> dword of 2 f16 (internal q/k/v storage; f16 > bf16 precision)
__device__ __forceinline__ unsigned pkh2(float a, float b){
    half2_t h; h[0] = (_Float16)a; h[1] = (_Float16)b;
    union { half2_t h; unsigned u; } c; c.h = h; return c.u;
}
__device__ __forceinline__ half2_t u2h2(unsigned u){
    union { unsigned u; half2_t h; } c; c.u = u; return c.h;
}
// mixed f16->f32 dot2: compiles to v_fma_mix_f32 pairs (no unpack insts)
__device__ __forceinline__ float dot2h(half2_t a, half2_t b, float c){
    return c + (float)a[0]*(float)b[0] + (float)a[1]*(float)b[1];
}
// f32 weight row (48 elems) dot f32x2-packed activations:
// 24 v_pk_fma_f32 (2 MAC/inst), zero unpack instructions.
__device__ __forceinline__ float dot48p(const f32x2* __restrict__ wr,
                                        const f32x2* __restrict__ xp){
    f32x2 a0 = {0.f, 0.f}, a1 = {0.f, 0.f};
    #pragma unroll
    for (int d = 0; d < 24; d += 2){
        a0 += wr[d]     * xp[d];
        a1 += wr[d + 1] * xp[d + 1];
    }
    f32x2 a = a0 + a1;
    return a[0] + a[1];
}

__device__ __forceinline__ int wstart(int i){
    // L=192, K=7, DIL=3 closed form of _window_starts
    if (i < 9) return i % 3;
    if (i >= 183) return 171 + (i % 3);
    return i - 9;
}

// ------------- Kernel B: convert weights (self-detecting dtype) -----------------
__global__ void convert_kernel(
    const void* p0, const void* p1, const void* p2, const void* p3,
    const void* p4, const void* p5, const void* p6, const void* p7,
    const void* p8, const void* p9, const void* p10, const void* p11,
    const void* p12, const ushort_t* __restrict__ xu, int* __restrict__ mode_out,
    float* __restrict__ wts, float* __restrict__ woutTf)
{
    __shared__ int sbad;
    if (threadIdx.x == 0) sbad = 0;
    __syncthreads();
    {   // 256-sample dtype sniff on x: bf16 N(0,1) never has |v|>=100
        unsigned u = xu[2*threadIdx.x];
        float f = __uint_as_float(u << 16);
        if (!(fabsf(f) < 100.f)) atomicAdd(&sbad, 1);
    }
    __syncthreads();
    const int md = (sbad > 16) ? 1 : 0;
    if (blockIdx.x == 0 && threadIdx.x == 0) mode_out[0] = md;

    const void* ps[13] = {p0,p1,p2,p3,p4,p5,p6,p7,p8,p9,p10,p11,p12};
    const int sz[13]  = {48,48,6912,144,338,2304,48,7,48,48,12192,2286,6096};
    const int off[13] = {O_LN1W,48,O_QKVW,O_QKVB,O_RPB,O_PROJW,O_PROJB,O_ECA,
                         O_LN2W,9897,O_WIN,O_WDW,O_WOUT};
    int b = blockIdx.x;
    if (b == 14){
        // f32 transposed w_out: woutTf[c*48 + o] = wout[o][c]
        if (md){
            const float* s = (const float*)p12;
            for (int i = threadIdx.x; i < 6096; i += 256){
                int c = i / 48, o = i - c*48;
                woutTf[i] = s[o*127 + c];
            }
        } else {
            const ushort_t* s = (const ushort_t*)p12;
            for (int i = threadIdx.x; i < 6096; i += 256){
                int c = i / 48, o = i - c*48;
                woutTf[i] = u2f(s[o*127 + c]);
            }
        }
        return;
    }
    if (b >= 13) return;
    int n = sz[b];
    float* dst = wts + off[b];
    if (md){
        const float* s = (const float*)ps[b];
        for (int i = threadIdx.x; i < n; i += 256) dst[i] = s[i];
    } else {
        const __hip_bfloat16* s = (const __hip_bfloat16*)ps[b];
        for (int i = threadIdx.x; i < n; i += 256) dst[i] = b2f(s[i]);
    }
}

// ------------- Kernel 1: LN1 + QKV proj (f32 wts, pk_fma) + ECA partials --------
// 576 blocks x 384 thr = 64 px * 6 wave-uniform r-groups (24 outputs each).
// q/k/v HEAD-PLANAR [head][px][24ch] f16.
__global__ __launch_bounds__(384) void ln1qkv_kernel(
    const void* __restrict__ x, const int* __restrict__ mode,
    const float* __restrict__ wts,
    ushort_t* __restrict__ q, ushort_t* __restrict__ k, ushort_t* __restrict__ v,
    float* __restrict__ chpart)
{
    __shared__ float sx[64*49];           // 12544 B

    const int tid  = threadIdx.x;
    const int px_l = tid & 63;
    const int r6   = __builtin_amdgcn_readfirstlane(tid >> 6);  // 0..5 wave-uniform
    const int p0   = blockIdx.x * 64;
    const int p    = p0 + px_l;

    // x tile load, planar-coalesced
    if (mode[0]){
        const float* xf = (const float*)x;
        for (int idx = tid; idx < 64*48; idx += 384){
            int c = idx >> 6, pl = idx & 63;
            sx[pl*49 + c] = xf[c*HW_ + p0 + pl];
        }
    } else {
        const __hip_bfloat16* xb = (const __hip_bfloat16*)x;
        for (int idx = tid; idx < 64*48; idx += 384){
            int c = idx >> 6, pl = idx & 63;
            sx[pl*49 + c] = b2f(xb[c*HW_ + p0 + pl]);
        }
    }
    __syncthreads();

    // activations as f32x2 pairs (static indices only -> stays in VGPRs)
    f32x2 xp[24];
    float mu = 0.f;
    #pragma unroll
    for (int c = 0; c < 24; c++){
        xp[c][0] = sx[px_l*49 + 2*c];
        xp[c][1] = sx[px_l*49 + 2*c + 1];
        mu += xp[c][0] + xp[c][1];
    }
    mu *= (1.f/48.f);
    float var = 0.f;
    #pragma unroll
    for (int c = 0; c < 24; c++){
        float d0 = xp[c][0]-mu, d1 = xp[c][1]-mu;
        var += d0*d0 + d1*d1;
    }
    var *= (1.f/48.f);
    float rs = rsqrtf(var + 1e-5f);
    #pragma unroll
    for (int c = 0; c < 24; c++){
        xp[c][0] = (xp[c][0]-mu)*rs*wts[O_LN1W + 2*c]   + wts[O_LN1W + 48 + 2*c];
        xp[c][1] = (xp[c][1]-mu)*rs*wts[O_LN1W + 2*c+1] + wts[O_LN1W + 48 + 2*c+1];
    }

    // ECA per-block partials: wave 0 has px 0..63 exactly once
    if (tid < 64){
        #pragma unroll
        for (int c = 0; c < 48; c++){
            float s = xp[c>>1][c&1];
            s += __shfl_xor(s, 1);  s += __shfl_xor(s, 2);  s += __shfl_xor(s, 4);
            s += __shfl_xor(s, 8);  s += __shfl_xor(s, 16); s += __shfl_xor(s, 32);
            if (tid == 0) chpart[blockIdx.x*48 + c] = s;
        }
    }

    const int rbase = r6 * 24;
    const float scale = (r6 < 2) ? 0.20412414523193154f : 1.0f;
    float ov[24];
    #pragma unroll 4
    for (int ro = 0; ro < 24; ro++){
        int r = rbase + ro;
        float acc = wts[O_QKVB + r]
                  + dot48p((const f32x2*)(wts + O_QKVW + r*48), xp);
        ov[ro] = acc * scale;
    }

    unsigned int pk[12];
    #pragma unroll
    for (int d = 0; d < 12; d++)
        pk[d] = pkh2(ov[2*d], ov[2*d+1]);          // f16 pack
    ushort_t* tp = (r6 >> 1) == 0 ? q : ((r6 >> 1) == 1 ? k : v);
    // head-planar: [head][px][24] — r6&1 is the head for this 24-ch group
    uint4* dst4 = (uint4*)(tp + (size_t)(r6 & 1)*(HW_*24) + (size_t)p*24);
    dst4[0] = make_uint4(pk[0], pk[1], pk[2],  pk[3]);
    dst4[1] = make_uint4(pk[4], pk[5], pk[6],  pk[7]);
    dst4[2] = make_uint4(pk[8], pk[9], pk[10], pk[11]);
}

// ------------- Kernel 2: fused partial reduction + ECA conv + sigmoid -----------
__global__ __launch_bounds__(256) void gatefuse_kernel(
    const float* __restrict__ chpart, const float* __restrict__ wts,
    float* __restrict__ gate)
{
    __shared__ float sm[48];
    const int t = threadIdx.x;
    if (t < 192){
        const int ch = t >> 2, qq = t & 3;
        float acc = 0.f;
        #pragma unroll 4
        for (int b = qq; b < NBLK1; b += 4)
            acc += chpart[b*48 + ch];
        acc += __shfl_xor(acc, 1);
        acc += __shfl_xor(acc, 2);
        if (qq == 0) sm[ch] = acc * (1.f / (float)HW_);
    }
    __syncthreads();
    if (t < 48){
        float a = 0.f;
        for (int kk = 0; kk < 7; kk++){
            int cc = t + kk - 3;
            if (cc >= 0 && cc < 48) a += wts[O_ECA + kk] * sm[cc];
        }
        gate[t] = 1.f / (1.f + expf(-a));
    }
}

// ------------- Kernel 3: attention + proj + residual + LN2 + pointwise1 ---------
// HALF-TILE fused: 1152 blocks x 256 thr = 32 px * 2 heads * 4 n-lanes.
// Doubles grid (2.25 -> 4.5 blocks/CU, 9 -> 18 waves/CU) to hide the gather's
// dependency latency — R9/R10/R12 isolated the gather as latency-bound at the
// 576-block grid cap (FETCH -2.7x, VALU -2x, layout changes all time-neutral).
// Keeps 4-wave blocks (R3's 8-wave coupling failed) and fusion (R5's split
// failed). Epilogue: 8 groups (tid>>5) x 6 proj ch / 32 pw1 ch — weight rows
// half-wave-uniform (2 addrs/wave, coalesced L1-hot vector loads).
__global__ __launch_bounds__(256) void attnfuse_kernel(
    const ushort_t* __restrict__ q, const ushort_t* __restrict__ k,
    const ushort_t* __restrict__ v, const float* __restrict__ wts,
    const float* __restrict__ gate,
    const void* __restrict__ x, const int* __restrict__ mode,
    float* __restrict__ x2, ushort_t* __restrict__ tout)
{
    __shared__ float srpb[338];          // both heads' rpb
    __shared__ float sa[32*49];          // attn out, then x2, fp32, pad-49

    // XCD swizzle: consecutive blockIdx round-robin onto 8 XCDs; give XCD j
    // the contiguous tiles [j*144, (j+1)*144). Bijective (NTILE2 % 8 == 0).
    const int bx   = (int)blockIdx.x;
    const int tile = (bx & 7) * (NTILE2 >> 3) + (bx >> 3);

    const int tid = threadIdx.x;
    for (int i0 = tid; i0 < 338; i0 += 256) srpb[i0] = wts[O_RPB + i0];
    __syncthreads();

    const int p4    = tid & 3;           // 4-way neighbor split
    const int head  = (tid >> 2) & 1;
    const int px_l  = tid >> 3;          // 0..31
    const int px    = tile * 32 + px_l;
    const int i = px / Wd, j = px % Wd;
    const int sti = wstart(i), stj = wstart(j);
    const int pbi = (sti - i) / 3 + 6;
    const int pbj = (stj - j) / 3 + 6;
    const float* rpb = srpb + head*169;
    const size_t hplane = (size_t)head * (HW_*24);

    half2_t qh[12];
    {
        const uint4* qp = (const uint4*)(q + hplane + (size_t)px*24);  // 16B aligned
        uint4 q0 = qp[0], q1 = qp[1], q2 = qp[2];
        qh[0]=u2h2(q0.x); qh[1]=u2h2(q0.y); qh[2] =u2h2(q0.z); qh[3] =u2h2(q0.w);
        qh[4]=u2h2(q1.x); qh[5]=u2h2(q1.y); qh[6] =u2h2(q1.z); qh[7] =u2h2(q1.w);
        qh[8]=u2h2(q2.x); qh[9]=u2h2(q2.y); qh[10]=u2h2(q2.z); qh[11]=u2h2(q2.w);
    }

    float s = 0.f;
    float acc[24];
    #pragma unroll
    for (int c = 0; c < 24; c++) acc[c] = 0.f;

    #pragma unroll 4
    for (int tt = 0; tt < 13; tt++){
        int n = 4*tt + p4;
        const bool bad = (n > 48);       // tt=12: only p4==0 valid
        if (bad) n = 48;
        int xx = (n * 147) >> 10;        // n/7 for n in [0,48]
        int yy = n - 7*xx;
        int ii = sti + 3*xx, jj = stj + 3*yy;
        const size_t nb = hplane + (size_t)(ii*Wd + jj)*24;
        const uint4* kp = (const uint4*)(k + nb);   // 16B aligned (48B records)
        const uint4* vp = (const uint4*)(v + nb);
        uint4 K0 = kp[0], K1 = kp[1], K2 = kp[2];
        uint4 V0 = vp[0], V1 = vp[1], V2 = vp[2];
        float d = 0.f;
        d = dot2h(u2h2(K0.x), qh[0],  d);
        d = dot2h(u2h2(K0.y), qh[1],  d);
        d = dot2h(u2h2(K0.z), qh[2],  d);
        d = dot2h(u2h2(K0.w), qh[3],  d);
        d = dot2h(u2h2(K1.x), qh[4],  d);
        d = dot2h(u2h2(K1.y), qh[5],  d);
        d = dot2h(u2h2(K1.z), qh[6],  d);
        d = dot2h(u2h2(K1.w), qh[7],  d);
        d = dot2h(u2h2(K2.x), qh[8],  d);
        d = dot2h(u2h2(K2.y), qh[9],  d);
        d = dot2h(u2h2(K2.z), qh[10], d);
        d = dot2h(u2h2(K2.w), qh[11], d);
        float sc = d + rpb[(pbi+xx)*13 + (pbj+yy)];
        sc = fminf(sc, 80.f);            // overflow guard (true |sc| ~ 1)
        if (bad) sc = -1e30f;            // exp -> exact 0
        float p = __expf(sc);
        s += p;
        half2_t vv;
        vv=u2h2(V0.x); acc[0] +=p*(float)vv[0]; acc[1] +=p*(float)vv[1];
        vv=u2h2(V0.y); acc[2] +=p*(float)vv[0]; acc[3] +=p*(float)vv[1];
        vv=u2h2(V0.z); acc[4] +=p*(float)vv[0]; acc[5] +=p*(float)vv[1];
        vv=u2h2(V0.w); acc[6] +=p*(float)vv[0]; acc[7] +=p*(float)vv[1];
        vv=u2h2(V1.x); acc[8] +=p*(float)vv[0]; acc[9] +=p*(float)vv[1];
        vv=u2h2(V1.y); acc[10]+=p*(float)vv[0]; acc[11]+=p*(float)vv[1];
        vv=u2h2(V1.z); acc[12]+=p*(float)vv[0]; acc[13]+=p*(float)vv[1];
        vv=u2h2(V1.w); acc[14]+=p*(float)vv[0]; acc[15]+=p*(float)vv[1];
        vv=u2h2(V2.x); acc[16]+=p*(float)vv[0]; acc[17]+=p*(float)vv[1];
        vv=u2h2(V2.y); acc[18]+=p*(float)vv[0]; acc[19]+=p*(float)vv[1];
        vv=u2h2(V2.z); acc[20]+=p*(float)vv[0]; acc[21]+=p*(float)vv[1];
        vv=u2h2(V2.w); acc[22]+=p*(float)vv[0]; acc[23]+=p*(float)vv[1];
    }

    // merge 4 disjoint n-lanes (plain sums; butterfly leaves all lanes merged)
    s += __shfl_xor(s, 1);
    s += __shfl_xor(s, 2);
    #pragma unroll
    for (int c = 0; c < 24; c++){
        acc[c] += __shfl_xor(acc[c], 1);
        acc[c] += __shfl_xor(acc[c], 2);
    }
    {
        const float inv = 1.f / s;
        // each p4 lane stores its 6-channel slice (static indices per branch)
        float* dst = sa + px_l*49 + head*24;
        if (p4 == 0){
            #pragma unroll
            for (int c = 0; c < 6; c++) dst[c] = acc[c] * inv;
        } else if (p4 == 1){
            #pragma unroll
            for (int c = 0; c < 6; c++) dst[6 + c] = acc[6 + c] * inv;
        } else if (p4 == 2){
            #pragma unroll
            for (int c = 0; c < 6; c++) dst[12 + c] = acc[12 + c] * inv;
        } else {
            #pragma unroll
            for (int c = 0; c < 6; c++) dst[18 + c] = acc[18 + c] * inv;
        }
    }
    __syncthreads();

    // ---- proj + gate + residual -> x2 (global + LDS), pk_fma dots ----
    const int px_l2 = tid & 31;
    const int grp   = tid >> 5;          // 0..7 (2 values per wave)
    const int px2   = tile * 32 + px_l2;

    f32x2 ar[24];
    #pragma unroll
    for (int c = 0; c < 24; c++){
        ar[c][0] = sa[px_l2*49 + 2*c];
        ar[c][1] = sa[px_l2*49 + 2*c + 1];
    }
    __syncthreads();                       // all sa reads done before overwrite

    const float* xf = (const float*)x;
    const __hip_bfloat16* xb = (const __hip_bfloat16*)x;
    const int md = mode[0];
    const int ob = grp * 6;
    #pragma unroll
    for (int oo = 0; oo < 6; oo++){
        int o = ob + oo;
        float accp = wts[O_PROJB + o]
                   + dot48p((const f32x2*)(wts + O_PROJW + o*48), ar);
        float res = md ? xf[o*HW_ + px2] : b2f(xb[o*HW_ + px2]);
        float xv = res + accp * gate[o];
        x2[o*HW_ + px2] = xv;
        sa[px_l2*49 + o] = xv;
    }
    __syncthreads();

    // ---- LN2 (from LDS) + pointwise1 (f32 wts, pk_fma) ----
    f32x2 xp[24];
    float mu = 0.f;
    #pragma unroll
    for (int c = 0; c < 24; c++){
        xp[c][0] = sa[px_l2*49 + 2*c];
        xp[c][1] = sa[px_l2*49 + 2*c + 1];
        mu += xp[c][0] + xp[c][1];
    }
    mu *= (1.f/48.f);
    float var = 0.f;
    #pragma unroll
    for (int c = 0; c < 24; c++){
        float d0 = xp[c][0]-mu, d1 = xp[c][1]-mu;
        var += d0*d0 + d1*d1;
    }
    var *= (1.f/48.f);
    float rs = rsqrtf(var + 1e-5f);
    #pragma unroll
    for (int c = 0; c < 24; c++){
        xp[c][0] = (xp[c][0]-mu)*rs*wts[O_LN2W + 2*c]   + wts[O_LN2W + 48 + 2*c];
        xp[c][1] = (xp[c][1]-mu)*rs*wts[O_LN2W + 2*c+1] + wts[O_LN2W + 48 + 2*c+1];
    }

    const int base = grp * 32;
    for (int t2 = 0; t2 < 32; t2 += 2){
        int o0 = base + t2;
        if (o0 >= 254) break;
        float accA = dot48p((const f32x2*)(wts + O_WIN + o0*48), xp);
        float accB = dot48p((const f32x2*)(wts + O_WIN + min(o0+1,253)*48), xp);
        tout[(size_t)o0*HW_ + px2] = f2u(accA);
        if (o0+1 < 254) tout[(size_t)(o0+1)*HW_ + px2] = f2u(accB);
    }
}

// ------------- Kernel 6: depthwise 3x3 + GeLU gating, 4 px/thread ---------------
__global__ __launch_bounds__(256) void dw_kernel(
    const ushort_t* __restrict__ t, const float* __restrict__ wts,
    ushort_t* __restrict__ g)
{
    const int ch = blockIdx.y;               // 0..126
    const int pp = (blockIdx.x * 256 + threadIdx.x) * 4;   // 4-aligned px
    const int i  = pp / Wd, j = pp % Wd;     // j%4==0, quad never crosses a row
    float w1[9], w2[9];
    #pragma unroll
    for (int s2 = 0; s2 < 9; s2++){
        w1[s2] = wts[O_WDW + ch*9 + s2];
        w2[s2] = wts[O_WDW + (ch+HIDc)*9 + s2];
    }
    const ushort_t* t1 = t + (size_t)ch * HW_;
    const ushort_t* t2 = t + (size_t)(ch+HIDc) * HW_;
    float a10=0.f,a11=0.f,a12=0.f,a13=0.f;
    float a20=0.f,a21=0.f,a22=0.f,a23=0.f;
    #pragma unroll
    for (int di = 0; di < 3; di++){
        int ii = i + di - 1;
        if (ii < 0 || ii >= 192) continue;
        int base = ii*Wd + j;
        float wa = w1[di*3], wb = w1[di*3+1], wc = w1[di*3+2];
        {
            uint2 mm = *(const uint2*)(t1 + base);          // cols j..j+3
            float c0,c1,c2,c3; up2(mm.x,c0,c1); up2(mm.y,c2,c3);
            float cm = (j > 0)     ? u2f(t1[base-1]) : 0.f;
            float cp = (j+4 < Wd)  ? u2f(t1[base+4]) : 0.f;
            a10 += wa*cm + wb*c0 + wc*c1;
            a11 += wa*c0 + wb*c1 + wc*c2;
            a12 += wa*c1 + wb*c2 + wc*c3;
            a13 += wa*c2 + wb*c3 + wc*cp;
        }
        wa = w2[di*3]; wb = w2[di*3+1]; wc = w2[di*3+2];
        {
            uint2 mm = *(const uint2*)(t2 + base);
            float c0,c1,c2,c3; up2(mm.x,c0,c1); up2(mm.y,c2,c3);
            float cm = (j > 0)     ? u2f(t2[base-1]) : 0.f;
            float cp = (j+4 < Wd)  ? u2f(t2[base+4]) : 0.f;
            a20 += wa*cm + wb*c0 + wc*c1;
            a21 += wa*c0 + wb*c1 + wc*c2;
            a22 += wa*c1 + wb*c2 + wc*c3;
            a23 += wa*c2 + wb*c3 + wc*cp;
        }
    }
    const float RS2 = 0.70710678118654752f;
    float g0 = a10 * 0.5f * (1.f + erff(a10 * RS2)) * a20;
    float g1 = a11 * 0.5f * (1.f + erff(a11 * RS2)) * a21;
    float g2 = a12 * 0.5f * (1.f + erff(a12 * RS2)) * a22;
    float g3 = a13 * 0.5f * (1.f + erff(a13 * RS2)) * a23;
    uint2 pk;
    pk.x = (unsigned)f2u(g0) | ((unsigned)f2u(g1) << 16);
    pk.y = (unsigned)f2u(g2) | ((unsigned)f2u(g3) << 16);
    *(uint2*)(g + (size_t)ch*HW_ + pp) = pk;      // pp%4==0 -> 8B aligned
}

// ------------- Kernel 7: pointwise2 (f32 woutT, pk_fma) + residual --------------
__global__ __launch_bounds__(128) void pw2_kernel(
    const ushort_t* __restrict__ g, const float* __restrict__ woutTf,
    const float* __restrict__ x2, void* __restrict__ outv,
    const int* __restrict__ mode)
{
    const int ob = blockIdx.y * 12;          // even -> f32x2 rows stay 8B-aligned
    const int p  = blockIdx.x * 128 + threadIdx.x;
    f32x2 acc2[6];
    #pragma unroll
    for (int d = 0; d < 6; d++) acc2[d] = (f32x2){0.f, 0.f};
    #pragma unroll 4
    for (int c = 0; c < 127; c++){
        float gv = u2f(g[(size_t)c*HW_ + p]);
        f32x2 gv2; gv2[0] = gv; gv2[1] = gv;
        // 12 f32 weights, wave-uniform address -> s_load; 6 v_pk_fma_f32
        const f32x2* w2 = (const f32x2*)(woutTf + c*48 + ob);
        #pragma unroll
        for (int d = 0; d < 6; d++) acc2[d] += w2[d] * gv2;
    }
    if (mode[0]){
        float* out = (float*)outv;
        #pragma unroll
        for (int o = 0; o < 12; o++){
            int oc = ob + o;
            out[(size_t)oc*HW_ + p] = x2[(size_t)oc*HW_ + p] + acc2[o>>1][o&1];
        }
    } else {
        __hip_bfloat16* out = (__hip_bfloat16*)outv;
        #pragma unroll
        for (int o = 0; o < 12; o++){
            int oc = ob + o;
            out[(size_t)oc*HW_ + p] =
                __float2bfloat16(x2[(size_t)oc*HW_ + p] + acc2[o>>1][o&1]);
        }
    }
}

extern "C" void kernel_launch(void* const* d_in, const int* in_sizes, int n_in,
                              void* d_out, int out_size, void* d_ws, size_t ws_size,
                              hipStream_t stream)
{
    (void)in_sizes; (void)n_in; (void)out_size;

    // layout (t separate from q/k/v: attnfuse writes t while q/k/v are live)
    char* ws = (char*)d_ws;
    ushort_t* q    = (ushort_t*)(ws);                 // 3,538,944
    ushort_t* k    = (ushort_t*)(ws + 3538944);
    ushort_t* v    = (ushort_t*)(ws + 7077888);       // ends 10,616,832
    float*    x2   = (float*)   (ws + 10616832);      // 7,077,888 -> 17,694,720
    ushort_t* t    = (ushort_t*)(ws + 17694720);      // 18,726,912 -> 36,421,632
    ushort_t* g    = (ushort_t*)(ws);                 // aliases q/k/v (dead by dw)
    float*    gate = (float*)   (ws + 36421632);      // 192 B
    int*      mode = (int*)     (ws + 36421824);
    float*    wts  = (float*)   (ws + 36421840);      // WTS_LEN*4 = 122,080
    float*    chpart=(float*)   (ws + 36543920);      // NBLK1*48*4 = 110,592
    float*    woutTf = (float*) (ws + 36654512);      // 24,384 B (f32, 8B-aligned)

    size_t need = 36654512 + 24384;
    if (ws_size < need) return;

    convert_kernel<<<15, 256, 0, stream>>>(
        d_in[1], d_in[2], d_in[3], d_in[4], d_in[5], d_in[6], d_in[7],
        d_in[8], d_in[9], d_in[10], d_in[11], d_in[12], d_in[13],
        (const ushort_t*)d_in[0], mode, wts, woutTf);

    ln1qkv_kernel<<<dim3(NBLK1), 384, 0, stream>>>(d_in[0], mode, wts,
                                                   q, k, v, chpart);
    gatefuse_kernel<<<1, 256, 0, stream>>>(chpart, wts, gate);
    attnfuse_kernel<<<dim3(NTILE2), 256, 0, stream>>>(q, k, v, wts, gate,
                                                      d_in[0], mode, x2, t);
    dw_kernel<<<dim3(HW_/1024, 127), 256, 0, stream>>>(t, wts, g);
    pw2_kernel<<<dim3(HW_/128, 4), 128, 0, stream>>>(g, woutTf, x2, d_out, mode);
}

// Round 14
// 228.395 us; speedup vs baseline: 1.1612x; 1.1612x over previous
//
#include <hip/hip_runtime.h>
#include <hip/hip_bf16.h>
#include <math.h>

#define HW_ (192*192)
#define Wd 192
#define HIDc 127
#define NBLK1 (HW_/64)   // 576 ln1qkv blocks

// fp32 weight-copy offsets inside ws "wts" region
// (O_WIN/O_WDW/O_WOUT shifted +1 so every weight row base is 8B-aligned.)
#define O_LN1W 0
#define O_QKVW 96
#define O_QKVB 7008
#define O_RPB  7152
#define O_PROJW 7490
#define O_PROJB 9794
#define O_ECA  9842
#define O_LN2W 9849
#define O_WIN  9946
#define O_WDW  22138
#define O_WOUT 24424
#define WTS_LEN 30520

typedef unsigned short ushort_t;
typedef _Float16 half2_t __attribute__((ext_vector_type(2)));
typedef float f32x2 __attribute__((ext_vector_type(2)));

__device__ __forceinline__ float b2f(__hip_bfloat16 v){ return __bfloat162float(v); }
__device__ __forceinline__ float u2f(ushort_t h){ return __uint_as_float(((unsigned)h)<<16); }
__device__ __forceinline__ ushort_t f2u(float f){
    __hip_bfloat16 h = __float2bfloat16(f);
    union { __hip_bfloat16 b; ushort_t u; } c; c.b = h; return c.u;
}
// unpack packed 2xbf16 (low index in low 16 bits)
__device__ __forceinline__ void up2(unsigned u, float& a, float& b){
    a = __uint_as_float(u << 16);
    b = __uint_as_float(u & 0xffff0000u);
}
// pack two f32 -> dword of 2 f16 (internal q/k/v storage; f16 > bf16 precision)
__device__ __forceinline__ unsigned pkh2(float a, float b){
    half2_t h; h[0] = (_Float16)a; h[1] = (_Float16)b;
    union { half2_t h; unsigned u; } c; c.h = h; return c.u;
}
__device__ __forceinline__ half2_t u2h2(unsigned u){
    union { unsigned u; half2_t h; } c; c.u = u; return c.h;
}
// mixed f16->f32 dot2: compiles to v_fma_mix_f32 pairs (no unpack insts)
__device__ __forceinline__ float dot2h(half2_t a, half2_t b, float c){
    return c + (float)a[0]*(float)b[0] + (float)a[1]*(float)b[1];
}
// f32 weight row (48 elems, wave-uniform addr -> s_load) dot f32x2-packed
// activations: 24 v_pk_fma_f32 (2 MAC/inst), zero unpack instructions.
__device__ __forceinline__ float dot48p(const f32x2* __restrict__ wr,
                                        const f32x2* __restrict__ xp){
    f32x2 a0 = {0.f, 0.f}, a1 = {0.f, 0.f};
    #pragma unroll
    for (int d = 0; d < 24; d += 2){
        a0 += wr[d]     * xp[d];
        a1 += wr[d + 1] * xp[d + 1];
    }
    f32x2 a = a0 + a1;
    return a[0] + a[1];
}

__device__ __forceinline__ int wstart(int i){
    // L=192, K=7, DIL=3 closed form of _window_starts
    if (i < 9) return i % 3;
    if (i >= 183) return 171 + (i % 3);
    return i - 9;
}

// ------------- Kernel B: convert weights (self-detecting dtype) -----------------
// All weights land as f32 in wts (consumed via s_load + v_pk_fma_f32);
// woutTf is the f32 transposed w_out copy for pw2.
__global__ void convert_kernel(
    const void* p0, const void* p1, const void* p2, const void* p3,
    const void* p4, const void* p5, const void* p6, const void* p7,
    const void* p8, const void* p9, const void* p10, const void* p11,
    const void* p12, const ushort_t* __restrict__ xu, int* __restrict__ mode_out,
    float* __restrict__ wts, float* __restrict__ woutTf)
{
    __shared__ int sbad;
    if (threadIdx.x == 0) sbad = 0;
    __syncthreads();
    {   // 256-sample dtype sniff on x: bf16 N(0,1) never has |v|>=100
        unsigned u = xu[2*threadIdx.x];
        float f = __uint_as_float(u << 16);
        if (!(fabsf(f) < 100.f)) atomicAdd(&sbad, 1);
    }
    __syncthreads();
    const int md = (sbad > 16) ? 1 : 0;
    if (blockIdx.x == 0 && threadIdx.x == 0) mode_out[0] = md;

    const void* ps[13] = {p0,p1,p2,p3,p4,p5,p6,p7,p8,p9,p10,p11,p12};
    const int sz[13]  = {48,48,6912,144,338,2304,48,7,48,48,12192,2286,6096};
    const int off[13] = {O_LN1W,48,O_QKVW,O_QKVB,O_RPB,O_PROJW,O_PROJB,O_ECA,
                         O_LN2W,9897,O_WIN,O_WDW,O_WOUT};
    int b = blockIdx.x;
    if (b == 14){
        // f32 transposed w_out: woutTf[c*48 + o] = wout[o][c]
        if (md){
            const float* s = (const float*)p12;
            for (int i = threadIdx.x; i < 6096; i += 256){
                int c = i / 48, o = i - c*48;
                woutTf[i] = s[o*127 + c];
            }
        } else {
            const ushort_t* s = (const ushort_t*)p12;
            for (int i = threadIdx.x; i < 6096; i += 256){
                int c = i / 48, o = i - c*48;
                woutTf[i] = u2f(s[o*127 + c]);
            }
        }
        return;
    }
    if (b >= 13) return;
    int n = sz[b];
    float* dst = wts + off[b];
    if (md){
        const float* s = (const float*)ps[b];
        for (int i = threadIdx.x; i < n; i += 256) dst[i] = s[i];
    } else {
        const __hip_bfloat16* s = (const __hip_bfloat16*)ps[b];
        for (int i = threadIdx.x; i < n; i += 256) dst[i] = b2f(s[i]);
    }
}

// ------------- Kernel 1: LN1 + QKV proj (f32 wts, pk_fma) + ECA partials --------
// 576 blocks x 384 thr = 64 px * 6 wave-uniform r-groups (24 outputs each).
__global__ __launch_bounds__(384) void ln1qkv_kernel(
    const void* __restrict__ x, const int* __restrict__ mode,
    const float* __restrict__ wts,
    ushort_t* __restrict__ q, ushort_t* __restrict__ k, ushort_t* __restrict__ v,
    float* __restrict__ chpart)
{
    __shared__ float sx[64*49];           // 12544 B

    const int tid  = threadIdx.x;
    const int px_l = tid & 63;
    const int r6   = __builtin_amdgcn_readfirstlane(tid >> 6);  // 0..5 wave-uniform
    const int p0   = blockIdx.x * 64;
    const int p    = p0 + px_l;

    // x tile load, planar-coalesced
    if (mode[0]){
        const float* xf = (const float*)x;
        for (int idx = tid; idx < 64*48; idx += 384){
            int c = idx >> 6, pl = idx & 63;
            sx[pl*49 + c] = xf[c*HW_ + p0 + pl];
        }
    } else {
        const __hip_bfloat16* xb = (const __hip_bfloat16*)x;
        for (int idx = tid; idx < 64*48; idx += 384){
            int c = idx >> 6, pl = idx & 63;
            sx[pl*49 + c] = b2f(xb[c*HW_ + p0 + pl]);
        }
    }
    __syncthreads();

    // activations as f32x2 pairs (static indices only -> stays in VGPRs)
    f32x2 xp[24];
    float mu = 0.f;
    #pragma unroll
    for (int c = 0; c < 24; c++){
        xp[c][0] = sx[px_l*49 + 2*c];
        xp[c][1] = sx[px_l*49 + 2*c + 1];
        mu += xp[c][0] + xp[c][1];
    }
    mu *= (1.f/48.f);
    float var = 0.f;
    #pragma unroll
    for (int c = 0; c < 24; c++){
        float d0 = xp[c][0]-mu, d1 = xp[c][1]-mu;
        var += d0*d0 + d1*d1;
    }
    var *= (1.f/48.f);
    float rs = rsqrtf(var + 1e-5f);
    #pragma unroll
    for (int c = 0; c < 24; c++){
        xp[c][0] = (xp[c][0]-mu)*rs*wts[O_LN1W + 2*c]   + wts[O_LN1W + 48 + 2*c];
        xp[c][1] = (xp[c][1]-mu)*rs*wts[O_LN1W + 2*c+1] + wts[O_LN1W + 48 + 2*c+1];
    }

    // ECA per-block partials: wave 0 has px 0..63 exactly once
    if (tid < 64){
        #pragma unroll
        for (int c = 0; c < 48; c++){
            float s = xp[c>>1][c&1];
            s += __shfl_xor(s, 1);  s += __shfl_xor(s, 2);  s += __shfl_xor(s, 4);
            s += __shfl_xor(s, 8);  s += __shfl_xor(s, 16); s += __shfl_xor(s, 32);
            if (tid == 0) chpart[blockIdx.x*48 + c] = s;
        }
    }

    const int rbase = r6 * 24;
    const float scale = (r6 < 2) ? 0.20412414523193154f : 1.0f;
    float ov[24];
    #pragma unroll 4
    for (int ro = 0; ro < 24; ro++){
        int r = rbase + ro;
        float acc = wts[O_QKVB + r]
                  + dot48p((const f32x2*)(wts + O_QKVW + r*48), xp);
        ov[ro] = acc * scale;
    }

    unsigned int pk[12];
    #pragma unroll
    for (int d = 0; d < 12; d++)
        pk[d] = pkh2(ov[2*d], ov[2*d+1]);          // f16 pack
    ushort_t* tp = (r6 >> 1) == 0 ? q : ((r6 >> 1) == 1 ? k : v);
    uint4* dst4 = (uint4*)(tp + (size_t)p*48 + (r6 & 1)*24);
    dst4[0] = make_uint4(pk[0], pk[1], pk[2],  pk[3]);
    dst4[1] = make_uint4(pk[4], pk[5], pk[6],  pk[7]);
    dst4[2] = make_uint4(pk[8], pk[9], pk[10], pk[11]);
}

// ------------- Kernel 2: fused partial reduction + ECA conv + sigmoid -----------
__global__ __launch_bounds__(256) void gatefuse_kernel(
    const float* __restrict__ chpart, const float* __restrict__ wts,
    float* __restrict__ gate)
{
    __shared__ float sm[48];
    const int t = threadIdx.x;
    if (t < 192){
        const int ch = t >> 2, qq = t & 3;
        float acc = 0.f;
        #pragma unroll 4
        for (int b = qq; b < NBLK1; b += 4)
            acc += chpart[b*48 + ch];
        acc += __shfl_xor(acc, 1);
        acc += __shfl_xor(acc, 2);
        if (qq == 0) sm[ch] = acc * (1.f / (float)HW_);
    }
    __syncthreads();
    if (t < 48){
        float a = 0.f;
        for (int kk = 0; kk < 7; kk++){
            int cc = t + kk - 3;
            if (cc >= 0 && cc < 48) a += wts[O_ECA + kk] * sm[cc];
        }
        gate[t] = 1.f / (1.f + expf(-a));
    }
}

// ------------- Kernel 3: attention + proj + residual + LN2 + pointwise1 ---------
// R2/R9/R10-verified structure (best total measured: 230.3us): 256 thr =
// 64 px * 2 heads * 2 parity lanes; scattered gather; XCD-aware bijective
// swizzle (R9: FETCH 30->11 MB); pk_fma epilogue with wave-uniform s_load
// weight rows (R10; R13 proved breaking uniformity costs ~40us).
__global__ __launch_bounds__(256) void attnfuse_kernel(
    const ushort_t* __restrict__ q, const ushort_t* __restrict__ k,
    const ushort_t* __restrict__ v, const float* __restrict__ wts,
    const float* __restrict__ gate,
    const void* __restrict__ x, const int* __restrict__ mode,
    float* __restrict__ x2, ushort_t* __restrict__ tout)
{
    __shared__ float srpb[338];          // both heads' rpb
    __shared__ float sa[64*49];          // attn out, then x2, fp32, pad-49

    // XCD swizzle: consecutive blockIdx round-robin onto 8 XCDs; this gives
    // XCD j the contiguous tiles [j*72, j*72+72). Bijective (NBLK1 % 8 == 0).
    const int bx   = (int)blockIdx.x;
    const int tile = (bx & 7) * (NBLK1 >> 3) + (bx >> 3);

    const int tid = threadIdx.x;
    for (int i0 = tid; i0 < 338; i0 += 256) srpb[i0] = wts[O_RPB + i0];
    __syncthreads();

    const int parity = tid & 1;
    const int head   = (tid >> 1) & 1;
    const int px_l   = tid >> 2;
    const int px     = tile * 64 + px_l;
    const int i = px / Wd, j = px % Wd;
    const int sti = wstart(i), stj = wstart(j);
    const int pbi = (sti - i) / 3 + 6;
    const int pbj = (stj - j) / 3 + 6;
    const int choff = head * 24;
    const float* rpb = srpb + head*169;

    half2_t qh[12];
    {
        const uint4* qp = (const uint4*)(q + (size_t)px*48 + choff);  // 16B aligned
        uint4 q0 = qp[0], q1 = qp[1], q2 = qp[2];
        qh[0]=u2h2(q0.x); qh[1]=u2h2(q0.y); qh[2] =u2h2(q0.z); qh[3] =u2h2(q0.w);
        qh[4]=u2h2(q1.x); qh[5]=u2h2(q1.y); qh[6] =u2h2(q1.z); qh[7] =u2h2(q1.w);
        qh[8]=u2h2(q2.x); qh[9]=u2h2(q2.y); qh[10]=u2h2(q2.z); qh[11]=u2h2(q2.w);
    }

    float s = 0.f;
    float acc[24];
    #pragma unroll
    for (int c = 0; c < 24; c++) acc[c] = 0.f;

    #pragma unroll 5
    for (int tt = 0; tt < 25; tt++){
        int n = 2*tt + parity;
        const bool inval = (n > 48);       // only parity=1, tt=24
        if (inval) n = 48;
        int xx = (n * 147) >> 10;          // n/7 for n in [0,48]
        int yy = n - 7*xx;
        int ii = sti + 3*xx, jj = stj + 3*yy;
        const size_t nb = (size_t)(ii*Wd + jj)*48 + choff;
        const uint4* kp = (const uint4*)(k + nb);   // 16B aligned
        const uint4* vp = (const uint4*)(v + nb);
        uint4 K0 = kp[0], K1 = kp[1], K2 = kp[2];
        uint4 V0 = vp[0], V1 = vp[1], V2 = vp[2];
        float d = 0.f;
        d = dot2h(u2h2(K0.x), qh[0],  d);
        d = dot2h(u2h2(K0.y), qh[1],  d);
        d = dot2h(u2h2(K0.z), qh[2],  d);
        d = dot2h(u2h2(K0.w), qh[3],  d);
        d = dot2h(u2h2(K1.x), qh[4],  d);
        d = dot2h(u2h2(K1.y), qh[5],  d);
        d = dot2h(u2h2(K1.z), qh[6],  d);
        d = dot2h(u2h2(K1.w), qh[7],  d);
        d = dot2h(u2h2(K2.x), qh[8],  d);
        d = dot2h(u2h2(K2.y), qh[9],  d);
        d = dot2h(u2h2(K2.z), qh[10], d);
        d = dot2h(u2h2(K2.w), qh[11], d);
        float sc = d + rpb[(pbi+xx)*13 + (pbj+yy)];
        sc = fminf(sc, 80.f);              // overflow guard (true |sc| ~ 1)
        if (inval) sc = -1e30f;            // exp -> exact 0
        float p = __expf(sc);
        s += p;
        half2_t vv;
        vv=u2h2(V0.x); acc[0] +=p*(float)vv[0]; acc[1] +=p*(float)vv[1];
        vv=u2h2(V0.y); acc[2] +=p*(float)vv[0]; acc[3] +=p*(float)vv[1];
        vv=u2h2(V0.z); acc[4] +=p*(float)vv[0]; acc[5] +=p*(float)vv[1];
        vv=u2h2(V0.w); acc[6] +=p*(float)vv[0]; acc[7] +=p*(float)vv[1];
        vv=u2h2(V1.x); acc[8] +=p*(float)vv[0]; acc[9] +=p*(float)vv[1];
        vv=u2h2(V1.y); acc[10]+=p*(float)vv[0]; acc[11]+=p*(float)vv[1];
        vv=u2h2(V1.z); acc[12]+=p*(float)vv[0]; acc[13]+=p*(float)vv[1];
        vv=u2h2(V1.w); acc[14]+=p*(float)vv[0]; acc[15]+=p*(float)vv[1];
        vv=u2h2(V2.x); acc[16]+=p*(float)vv[0]; acc[17]+=p*(float)vv[1];
        vv=u2h2(V2.y); acc[18]+=p*(float)vv[0]; acc[19]+=p*(float)vv[1];
        vv=u2h2(V2.z); acc[20]+=p*(float)vv[0]; acc[21]+=p*(float)vv[1];
        vv=u2h2(V2.w); acc[22]+=p*(float)vv[0]; acc[23]+=p*(float)vv[1];
    }

    // merge the two parity lanes (disjoint neighbor sets, plain sums)
    s += __shfl_xor(s, 1);
    const float inv = 1.f / s;
    float mg[12];
    #pragma unroll
    for (int c = 0; c < 12; c++){
        float mine   = parity ? acc[12+c] : acc[c];
        float theirs = parity ? acc[c]    : acc[12+c];
        mg[c] = (mine + __shfl_xor(theirs, 1)) * inv;   // uniform-exec shfl
    }
    {
        float* dst = sa + px_l*49 + choff + parity*12;
        #pragma unroll
        for (int c = 0; c < 12; c++) dst[c] = mg[c];
    }
    __syncthreads();

    // ---- proj + gate + residual -> x2 (global + LDS), pk_fma dots ----
    const int px_l2 = tid & 63;
    const int og    = __builtin_amdgcn_readfirstlane(tid >> 6);   // 0..3 uniform
    const int px2   = tile * 64 + px_l2;

    f32x2 ar[24];
    #pragma unroll
    for (int c = 0; c < 24; c++){
        ar[c][0] = sa[px_l2*49 + 2*c];
        ar[c][1] = sa[px_l2*49 + 2*c + 1];
    }
    __syncthreads();                       // all sa reads done before overwrite

    const float* xf = (const float*)x;
    const __hip_bfloat16* xb = (const __hip_bfloat16*)x;
    const int md = mode[0];
    const int ob = og * 12;
    #pragma unroll 2
    for (int oo = 0; oo < 12; oo++){
        int o = ob + oo;
        float accp = wts[O_PROJB + o]
                   + dot48p((const f32x2*)(wts + O_PROJW + o*48), ar);
        float res = md ? xf[o*HW_ + px2] : b2f(xb[o*HW_ + px2]);
        float xv = res + accp * gate[o];
        x2[o*HW_ + px2] = xv;
        sa[px_l2*49 + o] = xv;
    }
    __syncthreads();

    // ---- LN2 (from LDS) + pointwise1 (f32 wts, pk_fma) ----
    f32x2 xp[24];
    float mu = 0.f;
    #pragma unroll
    for (int c = 0; c < 24; c++){
        xp[c][0] = sa[px_l2*49 + 2*c];
        xp[c][1] = sa[px_l2*49 + 2*c + 1];
        mu += xp[c][0] + xp[c][1];
    }
    mu *= (1.f/48.f);
    float var = 0.f;
    #pragma unroll
    for (int c = 0; c < 24; c++){
        float d0 = xp[c][0]-mu, d1 = xp[c][1]-mu;
        var += d0*d0 + d1*d1;
    }
    var *= (1.f/48.f);
    float rs = rsqrtf(var + 1e-5f);
    #pragma unroll
    for (int c = 0; c < 24; c++){
        xp[c][0] = (xp[c][0]-mu)*rs*wts[O_LN2W + 2*c]   + wts[O_LN2W + 48 + 2*c];
        xp[c][1] = (xp[c][1]-mu)*rs*wts[O_LN2W + 2*c+1] + wts[O_LN2W + 48 + 2*c+1];
    }

    const int base = og * 64;
    for (int t2 = 0; t2 < 64; t2 += 2){
        int o0 = base + t2;
        if (o0 >= 254) break;
        float accA = dot48p((const f32x2*)(wts + O_WIN + o0*48), xp);
        float accB = dot48p((const f32x2*)(wts + O_WIN + min(o0+1,253)*48), xp);
        tout[(size_t)o0*HW_ + px2] = f2u(accA);
        if (o0+1 < 254) tout[(size_t)(o0+1)*HW_ + px2] = f2u(accB);
    }
}

// ------------- Kernel 6: depthwise 3x3 + GeLU gating, 4 px/thread ---------------
__global__ __launch_bounds__(256) void dw_kernel(
    const ushort_t* __restrict__ t, const float* __restrict__ wts,
    ushort_t* __restrict__ g)
{
    const int ch = blockIdx.y;               // 0..126
    const int pp = (blockIdx.x * 256 + threadIdx.x) * 4;   // 4-aligned px
    const int i  = pp / Wd, j = pp % Wd;     // j%4==0, quad never crosses a row
    float w1[9], w2[9];
    #pragma unroll
    for (int s2 = 0; s2 < 9; s2++){
        w1[s2] = wts[O_WDW + ch*9 + s2];
        w2[s2] = wts[O_WDW + (ch+HIDc)*9 + s2];
    }
    const ushort_t* t1 = t + (size_t)ch * HW_;
    const ushort_t* t2 = t + (size_t)(ch+HIDc) * HW_;
    float a10=0.f,a11=0.f,a12=0.f,a13=0.f;
    float a20=0.f,a21=0.f,a22=0.f,a23=0.f;
    #pragma unroll
    for (int di = 0; di < 3; di++){
        int ii = i + di - 1;
        if (ii < 0 || ii >= 192) continue;
        int base = ii*Wd + j;
        float wa = w1[di*3], wb = w1[di*3+1], wc = w1[di*3+2];
        {
            uint2 mm = *(const uint2*)(t1 + base);          // cols j..j+3
            float c0,c1,c2,c3; up2(mm.x,c0,c1); up2(mm.y,c2,c3);
            float cm = (j > 0)     ? u2f(t1[base-1]) : 0.f;
            float cp = (j+4 < Wd)  ? u2f(t1[base+4]) : 0.f;
            a10 += wa*cm + wb*c0 + wc*c1;
            a11 += wa*c0 + wb*c1 + wc*c2;
            a12 += wa*c1 + wb*c2 + wc*c3;
            a13 += wa*c2 + wb*c3 + wc*cp;
        }
        wa = w2[di*3]; wb = w2[di*3+1]; wc = w2[di*3+2];
        {
            uint2 mm = *(const uint2*)(t2 + base);
            float c0,c1,c2,c3; up2(mm.x,c0,c1); up2(mm.y,c2,c3);
            float cm = (j > 0)     ? u2f(t2[base-1]) : 0.f;
            float cp = (j+4 < Wd)  ? u2f(t2[base+4]) : 0.f;
            a20 += wa*cm + wb*c0 + wc*c1;
            a21 += wa*c0 + wb*c1 + wc*c2;
            a22 += wa*c1 + wb*c2 + wc*c3;
            a23 += wa*c2 + wb*c3 + wc*cp;
        }
    }
    const float RS2 = 0.70710678118654752f;
    float g0 = a10 * 0.5f * (1.f + erff(a10 * RS2)) * a20;
    float g1 = a11 * 0.5f * (1.f + erff(a11 * RS2)) * a21;
    float g2 = a12 * 0.5f * (1.f + erff(a12 * RS2)) * a22;
    float g3 = a13 * 0.5f * (1.f + erff(a13 * RS2)) * a23;
    uint2 pk;
    pk.x = (unsigned)f2u(g0) | ((unsigned)f2u(g1) << 16);
    pk.y = (unsigned)f2u(g2) | ((unsigned)f2u(g3) << 16);
    *(uint2*)(g + (size_t)ch*HW_ + pp) = pk;      // pp%4==0 -> 8B aligned
}

// ------------- Kernel 7: pointwise2 (f32 woutT, pk_fma) + residual --------------
__global__ __launch_bounds__(128) void pw2_kernel(
    const ushort_t* __restrict__ g, const float* __restrict__ woutTf,
    const float* __restrict__ x2, void* __restrict__ outv,
    const int* __restrict__ mode)
{
    const int ob = blockIdx.y * 12;          // even -> f32x2 rows stay 8B-aligned
    const int p  = blockIdx.x * 128 + threadIdx.x;
    f32x2 acc2[6];
    #pragma unroll
    for (int d = 0; d < 6; d++) acc2[d] = (f32x2){0.f, 0.f};
    #pragma unroll 4
    for (int c = 0; c < 127; c++){
        float gv = u2f(g[(size_t)c*HW_ + p]);
        f32x2 gv2; gv2[0] = gv; gv2[1] = gv;
        // 12 f32 weights, wave-uniform address -> s_load; 6 v_pk_fma_f32
        const f32x2* w2 = (const f32x2*)(woutTf + c*48 + ob);
        #pragma unroll
        for (int d = 0; d < 6; d++) acc2[d] += w2[d] * gv2;
    }
    if (mode[0]){
        float* out = (float*)outv;
        #pragma unroll
        for (int o = 0; o < 12; o++){
            int oc = ob + o;
            out[(size_t)oc*HW_ + p] = x2[(size_t)oc*HW_ + p] + acc2[o>>1][o&1];
        }
    } else {
        __hip_bfloat16* out = (__hip_bfloat16*)outv;
        #pragma unroll
        for (int o = 0; o < 12; o++){
            int oc = ob + o;
            out[(size_t)oc*HW_ + p] =
                __float2bfloat16(x2[(size_t)oc*HW_ + p] + acc2[o>>1][o&1]);
        }
    }
}

extern "C" void kernel_launch(void* const* d_in, const int* in_sizes, int n_in,
                              void* d_out, int out_size, void* d_ws, size_t ws_size,
                              hipStream_t stream)
{
    (void)in_sizes; (void)n_in; (void)out_size;

    // layout (t separate from q/k/v: attnfuse writes t while q/k/v are live)
    char* ws = (char*)d_ws;
    ushort_t* q    = (ushort_t*)(ws);                 // 3,538,944
    ushort_t* k    = (ushort_t*)(ws + 3538944);
    ushort_t* v    = (ushort_t*)(ws + 7077888);       // ends 10,616,832
    float*    x2   = (float*)   (ws + 10616832);      // 7,077,888 -> 17,694,720
    ushort_t* t    = (ushort_t*)(ws + 17694720);      // 18,726,912 -> 36,421,632
    ushort_t* g    = (ushort_t*)(ws);                 // aliases q/k/v (dead by dw)
    float*    gate = (float*)   (ws + 36421632);      // 192 B
    int*      mode = (int*)     (ws + 36421824);
    float*    wts  = (float*)   (ws + 36421840);      // WTS_LEN*4 = 122,080
    float*    chpart=(float*)   (ws + 36543920);      // NBLK1*48*4 = 110,592
    float*    woutTf = (float*) (ws + 36654512);      // 24,384 B (f32, 8B-aligned)

    size_t need = 36654512 + 24384;
    if (ws_size < need) return;

    convert_kernel<<<15, 256, 0, stream>>>(
        d_in[1], d_in[2], d_in[3], d_in[4], d_in[5], d_in[6], d_in[7],
        d_in[8], d_in[9], d_in[10], d_in[11], d_in[12], d_in[13],
        (const ushort_t*)d_in[0], mode, wts, woutTf);

    ln1qkv_kernel<<<dim3(NBLK1), 384, 0, stream>>>(d_in[0], mode, wts,
                                                   q, k, v, chpart);
    gatefuse_kernel<<<1, 256, 0, stream>>>(chpart, wts, gate);
    attnfuse_kernel<<<dim3(NBLK1), 256, 0, stream>>>(q, k, v, wts, gate,
                                                     d_in[0], mode, x2, t);
    dw_kernel<<<dim3(HW_/1024, 127), 256, 0, stream>>>(t, wts, g);
    pw2_kernel<<<dim3(HW_/128, 4), 128, 0, stream>>>(g, woutTf, x2, d_out, mode);
}